// Round 4
// baseline (235.748 us; speedup 1.0000x reference)
//
#include <hip/hip_runtime.h>

#define HDIM 64

// ---------------- small helpers ----------------

__device__ __forceinline__ int lbound(const int* __restrict__ b, int n, int v) {
    int lo = 0, hi = n;
    while (lo < hi) { int m = (lo + hi) >> 1; if (b[m] < v) lo = m + 1; else hi = m; }
    return lo;
}

// HW_REG_XCC_ID = 20 (gfx940+), read 32 bits: imm = (31<<11) | 20
__device__ __forceinline__ unsigned xcc_id() {
    return __builtin_amdgcn_s_getreg(63508) & 7u;
}

// ---------------- kernels ----------------

// Histogram + rank into per-XCD private copies. Workgroup-scope atomics
// execute at the local XCD's L2 (not the memory-side coherence point);
// per-XCD privatization via XCC_ID makes this race-free across XCDs.
__global__ void k_hist8(const int* __restrict__ row, const int* __restrict__ col,
                        int* __restrict__ deg8, int* __restrict__ cnt8,
                        int* __restrict__ rank, int E, int N) {
    int e = blockIdx.x * blockDim.x + threadIdx.x;
    unsigned xcd = xcc_id();
    if (e < E) {
        __hip_atomic_fetch_add(&deg8[xcd * N + row[e]], 1,
                               __ATOMIC_RELAXED, __HIP_MEMORY_SCOPE_WORKGROUP);
        int r = __hip_atomic_fetch_add(&cnt8[xcd * N + col[e]], 1,
                                       __ATOMIC_RELAXED, __HIP_MEMORY_SCOPE_WORKGROUP);
        rank[e] = (int)((xcd << 24) | (unsigned)r);
    }
}

// Per node: deg total -> dis; per-XCD cnt counts -> exclusive offsets (in
// place) + total into cnt.
__global__ void k_xscan(const int* __restrict__ deg8, int* __restrict__ cnt8,
                        int* __restrict__ cnt, float* __restrict__ dis, int N) {
    int i = blockIdx.x * blockDim.x + threadIdx.x;
    if (i >= N) return;
    int d = 0;
    #pragma unroll
    for (int xx = 0; xx < 8; ++xx) d += deg8[xx * N + i];
    dis[i] = d > 0 ? rsqrtf((float)d) : 0.0f;
    int off = 0;
    #pragma unroll
    for (int xx = 0; xx < 8; ++xx) {
        int v = cnt8[xx * N + i];
        cnt8[xx * N + i] = off;
        off += v;
    }
    cnt[i] = off;
}

// Exclusive scan of cnt, 2-level. Level 1: per-1024 block scan.
__global__ __launch_bounds__(1024) void k_scan1(const int* __restrict__ cnt,
                                                int* __restrict__ start,
                                                int* __restrict__ bsum, int n) {
    __shared__ int sh[1024];
    int i = blockIdx.x * 1024 + threadIdx.x;
    int v = (i < n) ? cnt[i] : 0;
    sh[threadIdx.x] = v;
    __syncthreads();
    for (int off = 1; off < 1024; off <<= 1) {
        int t = 0;
        if (threadIdx.x >= off) t = sh[threadIdx.x - off];
        __syncthreads();
        sh[threadIdx.x] += t;
        __syncthreads();
    }
    if (i < n) start[i] = sh[threadIdx.x] - v;   // exclusive within block
    if (threadIdx.x == 1023) bsum[blockIdx.x] = sh[1023];
}

// Level 2: one wave, shuffle exclusive scan over block sums (nb <= 64).
__global__ void k_scan2(int* __restrict__ bsum, int nb) {
    int lane = threadIdx.x;
    if (lane >= 64) return;
    int v = (lane < nb) ? bsum[lane] : 0;
    int incl = v;
    #pragma unroll
    for (int off = 1; off < 64; off <<= 1) {
        int u = __shfl_up(incl, off, 64);
        if (lane >= off) incl += u;
    }
    if (lane < nb) bsum[lane] = incl - v;
}

// Level 3: add block offsets.
__global__ void k_scan3(int* __restrict__ start, const int* __restrict__ bsum, int n) {
    int i = blockIdx.x * blockDim.x + threadIdx.x;
    if (i < n) start[i] += bsum[i >> 10];
}

// Fill CSR: er[start[c] + xcd_offset[c] + rank] = row(e). Pure scattered write.
__global__ void k_fill(const int* __restrict__ row, const int* __restrict__ col,
                       const int* __restrict__ start, const int* __restrict__ cnt8off,
                       const int* __restrict__ rank, int* __restrict__ er, int E, int N) {
    int e = blockIdx.x * blockDim.x + threadIdx.x;
    if (e < E) {
        int c = col[e];
        unsigned rk = (unsigned)rank[e];
        unsigned xcd = rk >> 24;
        er[start[c] + cnt8off[xcd * N + c] + (int)(rk & 0xFFFFFFu)] = row[e];
    }
}

// Gather 1: Tx[i][:] = sum over in-edges of (-dis[r]*dis[i]) * x[r][:]
// One wave per node; 4 lane-quarters each handle every 4th edge with float4
// row loads (16B/lane), combined across quarters by shuffle at the end.
__global__ __launch_bounds__(256) void k_gather1(const int* __restrict__ er,
                                                 const int* __restrict__ start,
                                                 const int* __restrict__ cnt,
                                                 const float* __restrict__ dis,
                                                 const float* __restrict__ x,
                                                 float* __restrict__ Tx, int n) {
    int i = blockIdx.x * 4 + (threadIdx.x >> 6);
    if (i >= n) return;
    int lane = threadIdx.x & 63;
    int q = lane >> 4;
    int s4 = (lane & 15) * 4;
    int s = start[i], nd = cnt[i];
    float di = dis[i];
    float4 acc = make_float4(0.f, 0.f, 0.f, 0.f);
    int k = q;
    for (; k + 4 < nd; k += 8) {
        int r0 = er[s + k], r1 = er[s + k + 4];
        float w0 = -dis[r0] * di, w1 = -dis[r1] * di;
        float4 v0 = *reinterpret_cast<const float4*>(&x[(size_t)r0 * HDIM + s4]);
        float4 v1 = *reinterpret_cast<const float4*>(&x[(size_t)r1 * HDIM + s4]);
        acc.x = fmaf(w0, v0.x, acc.x); acc.y = fmaf(w0, v0.y, acc.y);
        acc.z = fmaf(w0, v0.z, acc.z); acc.w = fmaf(w0, v0.w, acc.w);
        acc.x = fmaf(w1, v1.x, acc.x); acc.y = fmaf(w1, v1.y, acc.y);
        acc.z = fmaf(w1, v1.z, acc.z); acc.w = fmaf(w1, v1.w, acc.w);
    }
    if (k < nd) {
        int r0 = er[s + k];
        float w0 = -dis[r0] * di;
        float4 v0 = *reinterpret_cast<const float4*>(&x[(size_t)r0 * HDIM + s4]);
        acc.x = fmaf(w0, v0.x, acc.x); acc.y = fmaf(w0, v0.y, acc.y);
        acc.z = fmaf(w0, v0.z, acc.z); acc.w = fmaf(w0, v0.w, acc.w);
    }
    #pragma unroll
    for (int off = 16; off <= 32; off <<= 1) {
        acc.x += __shfl_xor(acc.x, off, 64);
        acc.y += __shfl_xor(acc.y, off, 64);
        acc.z += __shfl_xor(acc.z, off, 64);
        acc.w += __shfl_xor(acc.w, off, 64);
    }
    if (q == 0) *reinterpret_cast<float4*>(&Tx[(size_t)i * HDIM + s4]) = acc;
}

// h = x@W1[0] + Tx1@W1[1] + b1, in-place over Tx1, grid-stride; per-block
// column sum/sumsq accumulated in registers and atomically merged at the end
// (fuses the former k_stats pass).
__global__ __launch_bounds__(256) void k_gemm1(const float* __restrict__ x,
                                               float* __restrict__ TxH,
                                               const float* __restrict__ W1,
                                               const float* __restrict__ b1,
                                               float* __restrict__ stats, int n) {
    __shared__ float Ws[2 * HDIM * HDIM];       // 32 KB
    __shared__ float xs[4][HDIM];
    __shared__ float ts[4][HDIM];
    int tid = threadIdx.x;
    for (int idx = tid; idx < 2 * HDIM * HDIM; idx += 256) Ws[idx] = W1[idx];

    int rr = tid >> 6;
    int j  = tid & 63;
    float bj = b1[j];
    const float* w0 = Ws;
    const float* w1 = Ws + HDIM * HDIM;
    float sacc = 0.f, ssacc = 0.f;

    for (int base = blockIdx.x * 4; base < n; base += gridDim.x * 4) {
        int r = base + rr;
        __syncthreads();
        if (r < n) {
            xs[rr][j] = x[(size_t)r * HDIM + j];
            ts[rr][j] = TxH[(size_t)r * HDIM + j];
        }
        __syncthreads();
        if (r < n) {
            float acc = bj;
            #pragma unroll 8
            for (int k = 0; k < HDIM; ++k) {
                acc = fmaf(xs[rr][k], w0[k * HDIM + j], acc);
                acc = fmaf(ts[rr][k], w1[k * HDIM + j], acc);
            }
            TxH[(size_t)r * HDIM + j] = acc;
            sacc += acc;
            ssacc = fmaf(acc, acc, ssacc);
        }
    }
    __syncthreads();
    xs[rr][j] = sacc;
    ts[rr][j] = ssacc;
    __syncthreads();
    if (rr == 0) {
        float s  = xs[0][j] + xs[1][j] + xs[2][j] + xs[3][j];
        float ss = ts[0][j] + ts[1][j] + ts[2][j] + ts[3][j];
        atomicAdd(&stats[j], s);
        atomicAdd(&stats[64 + j], ss);
    }
}

// BN scale/shift, u0 = W2[0]@linW, u1 = W2[1]@linW, c0 = b2.linW + linb
__global__ void k_prep(const float* __restrict__ stats,
                       const float* __restrict__ gamma, const float* __restrict__ beta,
                       const float* __restrict__ W2, const float* __restrict__ b2,
                       const float* __restrict__ linW, const float* __restrict__ linb,
                       float* __restrict__ scale, float* __restrict__ shift,
                       float* __restrict__ u0, float* __restrict__ u1,
                       float* __restrict__ c0, int n) {
    int k = threadIdx.x;
    if (k >= HDIM) return;
    float inv_n = 1.0f / (float)n;
    float mu  = stats[k] * inv_n;
    float var = stats[64 + k] * inv_n - mu * mu;
    float rs  = rsqrtf(var + 1e-5f);
    float sc  = rs * gamma[k];
    scale[k] = sc;
    shift[k] = beta[k] - mu * sc;
    float a0 = 0.f, a1 = 0.f;
    #pragma unroll 8
    for (int j = 0; j < HDIM; ++j) {
        float lw = linW[j];
        a0 = fmaf(W2[k * HDIM + j], lw, a0);
        a1 = fmaf(W2[HDIM * HDIM + k * HDIM + j], lw, a1);
    }
    u0[k] = a0;
    u1[k] = a1;
    if (k == 0) {
        float c = linb[0];
        for (int j = 0; j < HDIM; ++j) c = fmaf(b2[j], linW[j], c);
        c0[0] = c;
    }
}

// Per node: BN + LeakyReLU, a[i]=y.u0, t[i]=y.u1 (wave shuffle reduce).
__global__ __launch_bounds__(256) void k_node(const float* __restrict__ h,
                                              const float* __restrict__ scale,
                                              const float* __restrict__ shift,
                                              const float* __restrict__ u0,
                                              const float* __restrict__ u1,
                                              float* __restrict__ a, float* __restrict__ t,
                                              int n) {
    int i = blockIdx.x * 4 + (threadIdx.x >> 6);
    if (i >= n) return;
    int j = threadIdx.x & 63;
    float v = fmaf(h[(size_t)i * HDIM + j], scale[j], shift[j]);
    v = v >= 0.f ? v : 0.01f * v;
    float p0 = v * u0[j];
    float p1 = v * u1[j];
    #pragma unroll
    for (int off = 32; off > 0; off >>= 1) {
        p0 += __shfl_xor(p0, off, 64);
        p1 += __shfl_xor(p1, off, 64);
    }
    if (j == 0) { a[i] = p0; t[i] = p1; }
}

// Gather 2 (scalar): s2[i] = a[i] + sum over in-edges of (-dis[r]*dis[i]) * t[r]
__global__ void k_gather2(const int* __restrict__ er, const int* __restrict__ start,
                          const int* __restrict__ cnt, const float* __restrict__ dis,
                          const float* __restrict__ t, const float* __restrict__ a,
                          float* __restrict__ s2, int n) {
    int i = blockIdx.x * blockDim.x + threadIdx.x;
    if (i >= n) return;
    int s = start[i], nd = cnt[i];
    float di = dis[i];
    float acc = a[i];
    int k = 0;
    for (; k + 1 < nd; k += 2) {
        int r0 = er[s + k], r1 = er[s + k + 1];
        float v0 = -dis[r0] * di * t[r0];
        float v1 = -dis[r1] * di * t[r1];
        acc += v0 + v1;
    }
    if (k < nd) {
        int r0 = er[s + k];
        acc = fmaf(-dis[r0] * di, t[r0], acc);
    }
    s2[i] = acc;
}

// Pool: one block per graph; batch is sorted -> binary search the range.
__global__ __launch_bounds__(256) void k_pool2(const float* __restrict__ s2,
                                               const int* __restrict__ batch,
                                               const float* __restrict__ c0,
                                               const float* __restrict__ linb,
                                               float* __restrict__ out, int n) {
    int g = blockIdx.x;
    int lo = lbound(batch, n, g);
    int hi = lbound(batch, n, g + 1);
    float s = 0.f;
    for (int i = lo + threadIdx.x; i < hi; i += 256) s += s2[i];
    __shared__ float red[256];
    red[threadIdx.x] = s;
    __syncthreads();
    for (int off = 128; off > 0; off >>= 1) {
        if (threadIdx.x < off) red[threadIdx.x] += red[threadIdx.x + off];
        __syncthreads();
    }
    if (threadIdx.x == 0) {
        int cntg = hi - lo;
        out[g] = cntg > 0 ? red[0] / (float)cntg + c0[0] : linb[0];
    }
}

// ---------------- launch ----------------

extern "C" void kernel_launch(void* const* d_in, const int* in_sizes, int n_in,
                              void* d_out, int out_size, void* d_ws, size_t ws_size,
                              hipStream_t stream) {
    const float* x     = (const float*)d_in[0];
    const int*   eidx  = (const int*)d_in[1];
    const int*   batch = (const int*)d_in[2];
    const float* W1    = (const float*)d_in[3];
    const float* b1    = (const float*)d_in[4];
    const float* W2    = (const float*)d_in[5];
    const float* b2    = (const float*)d_in[6];
    const float* gamma = (const float*)d_in[7];
    const float* beta  = (const float*)d_in[8];
    const float* linW  = (const float*)d_in[9];
    const float* linb  = (const float*)d_in[10];
    float* out = (float*)d_out;

    const int N = in_sizes[0] / HDIM;       // 50000
    const int E = in_sizes[1] / 2;          // 800000
    const int G = out_size;                 // 100
    const int NB = (N + 1023) / 1024;       // scan blocks (49 <= 64)

    const int* row = eidx;
    const int* col = eidx + E;

    // ---- workspace layout ----
    // TxH region first; deg8/cnt8/rank overlay it (all dead before gather1
    // writes TxH). 16N + E ints <= 64N floats for N=50k, E=800k.
    char* wsb = (char*)d_ws;
    float* TxH   = (float*)wsb;               wsb += (size_t)N * HDIM * 4;
    int*   deg8  = (int*)TxH;                     // 8N, hist8 -> xscan
    int*   cnt8  = deg8 + (size_t)8 * N;          // 8N, hist8 -> fill
    int*   rank  = cnt8 + (size_t)8 * N;          // E,  hist8 -> fill
    int*   cnt   = (int*)wsb;                 wsb += (size_t)N * 4;
    int*   start = (int*)wsb;                 wsb += (size_t)N * 4;
    int*   bsum  = (int*)wsb;                 wsb += (size_t)NB * 4 + 64;
    int*   er    = (int*)wsb;                 wsb += (size_t)E * 4;
    float* dis   = (float*)wsb;               wsb += (size_t)N * 4;
    float* a     = (float*)wsb;               wsb += (size_t)N * 4;
    float* t     = (float*)wsb;               wsb += (size_t)N * 4;
    float* s2    = (float*)wsb;               wsb += (size_t)N * 4;
    float* stats = (float*)wsb;               wsb += 128 * 4;
    float* scale = (float*)wsb;               wsb += HDIM * 4;
    float* shift = (float*)wsb;               wsb += HDIM * 4;
    float* u0    = (float*)wsb;               wsb += HDIM * 4;
    float* u1    = (float*)wsb;               wsb += HDIM * 4;
    float* c0    = (float*)wsb;               wsb += 64;

    hipMemsetAsync(deg8, 0, (size_t)16 * N * 4, stream);   // deg8 + cnt8
    hipMemsetAsync(stats, 0, 128 * 4, stream);

    k_hist8<<<(E + 255) / 256, 256, 0, stream>>>(row, col, deg8, cnt8, rank, E, N);
    k_xscan<<<(N + 255) / 256, 256, 0, stream>>>(deg8, cnt8, cnt, dis, N);
    k_scan1<<<NB, 1024, 0, stream>>>(cnt, start, bsum, N);
    k_scan2<<<1, 64, 0, stream>>>(bsum, NB);
    k_scan3<<<(N + 255) / 256, 256, 0, stream>>>(start, bsum, N);
    k_fill<<<(E + 255) / 256, 256, 0, stream>>>(row, col, start, cnt8, rank, er, E, N);
    k_gather1<<<(N + 3) / 4, 256, 0, stream>>>(er, start, cnt, dis, x, TxH, N);
    k_gemm1<<<1024, 256, 0, stream>>>(x, TxH, W1, b1, stats, N);
    k_prep<<<1, 64, 0, stream>>>(stats, gamma, beta, W2, b2, linW, linb,
                                 scale, shift, u0, u1, c0, N);
    k_node<<<(N + 3) / 4, 256, 0, stream>>>(TxH, scale, shift, u0, u1, a, t, N);
    k_gather2<<<(N + 255) / 256, 256, 0, stream>>>(er, start, cnt, dis, t, a, s2, N);
    k_pool2<<<G, 256, 0, stream>>>(s2, batch, c0, linb, out, N);
}